// Round 14
// baseline (682.728 us; speedup 1.0000x reference)
//
#include <hip/hip_runtime.h>

#define NN 4096
#define DD 64
#define NBLK 256      // block b owns f-rows and g-rows [16b, 16b+16)
#define NTHR 1024
#define NWAVE 16
#define ITERS 50

typedef __attribute__((ext_vector_type(8))) short short8;
typedef __attribute__((ext_vector_type(4))) float f32x4;
typedef _Float16 half2v __attribute__((ext_vector_type(2)));

#define C2f     0.4808983469629878f   /* 1/(eps*ln2), eps=3 */
#define EPSLN2f 2.0794415416798359f   /* eps*ln2 */
#define TWELVEf 12.0f                 /* log2(4096) marginal term */

#define LLC_LDU(p)    __hip_atomic_load((p), __ATOMIC_RELAXED, __HIP_MEMORY_SCOPE_AGENT)
#define LLC_STU(p, v) __hip_atomic_store((p), (v), __ATOMIC_RELAXED, __HIP_MEMORY_SCOPE_AGENT)

__device__ inline short bf16_of(float f) {
  unsigned u = __float_as_uint(f);
  u += 0x7fffu + ((u >> 16) & 1u);   // RTNE, inputs finite
  return (short)(u >> 16);
}

__device__ inline void pollbar(unsigned* bar, unsigned target) {
  while (__hip_atomic_load(bar, __ATOMIC_RELAXED, __HIP_MEMORY_SCOPE_AGENT) < target)
    __builtin_amdgcn_s_sleep(2);
}
__device__ inline void arrive(unsigned* cnt, int grp, unsigned* bar, unsigned phase) {
  unsigned old = atomicAdd(&cnt[grp << 5], 1u);
  if (old == (phase << 5) - 1u) atomicAdd(bar, 1u);
}

// publish-index -> tag in {1,2,3}; 0 (memset state) never matches; a slot at index h
// is only overwritten (h+2) after ALL consumers passed the h+1 all-to-all, so a
// reader expecting h can never see a same-tag h+6 value.
__device__ inline unsigned tag_of(int h) { return (unsigned)(h % 3) + 1u; }

// issue 4 slot loads (this wave's own needed columns)
__device__ __forceinline__ void load4(unsigned (&v)[4], unsigned* __restrict__ src, int base) {
#pragma unroll
  for (int q = 0; q < 4; ++q) v[q] = LLC_LDU(src + base + (q << 8));
}
// parallel-retry until all 4 carry tagIn
__device__ __forceinline__ void waitready(unsigned (&v)[4], unsigned* __restrict__ src,
                                          int base, unsigned tagIn) {
  for (;;) {
    unsigned miss = 0;
#pragma unroll
    for (int q = 0; q < 4; ++q) miss |= ((v[q] & 3u) != tagIn) ? (1u << q) : 0u;
    if (!miss) break;
    __builtin_amdgcn_s_sleep(1);
#pragma unroll
    for (int q = 0; q < 4; ++q)
      if (miss & (1u << q)) v[q] = LLC_LDU(src + base + (q << 8));
  }
}

// shfl-reduce 4 row-partials, LDS-atomic accumulate, wave-counter finish:
// the LAST wave to arrive computes log + publish; others continue immediately.
__device__ __forceinline__ void reduce_finish(float (&sum)[4], int buf,
                                              unsigned* __restrict__ outSlots,
                                              int i0, int lane, unsigned tagOut,
                                              bool last, float* __restrict__ outp,
                                              const float* sh_sq,
                                              float* red, unsigned* wcnt) {
#pragma unroll
  for (int o = 1; o <= 8; o <<= 1)
#pragma unroll
    for (int r = 0; r < 4; ++r) sum[r] += __shfl_xor(sum[r], o);
  if ((lane & 15) == 0)
#pragma unroll
    for (int r = 0; r < 4; ++r)
      atomicAdd(&red[buf * 16 + ((lane >> 4) << 2) + r], sum[r]);
  unsigned old = 0;
  if (lane == 0)
    old = __hip_atomic_fetch_add(&wcnt[buf], 1u, __ATOMIC_ACQ_REL,
                                 __HIP_MEMORY_SCOPE_WORKGROUP);
  old = __shfl(old, 0);
  if (old == NWAVE - 1u) {            // finisher wave (the natural straggler)
    if (lane < 16) {
      const float t  = red[buf * 16 + lane];
      const float bc = TWELVEf - __builtin_amdgcn_logf(t);   // v_log_f32 = log2
      LLC_STU(outSlots + i0 + lane, (__float_as_uint(bc) & ~3u) | tagOut);
      red[buf * 16 + lane] = 0.f;     // re-arm for phase+2 (gated by all-to-all)
      if (last) outp[i0 + lane] = sh_sq[lane] + EPSLN2f * bc;
    }
    if (lane == 0)                    // reset AFTER zeros (release orders LDS)
      __hip_atomic_store(&wcnt[buf], 0u, __ATOMIC_RELEASE,
                         __HIP_MEMORY_SCOPE_WORKGROUP);
  }
}

__global__ __launch_bounds__(NTHR, 4)   // 1 block/CU (128 KB LDS also enforces this)
void sink_kernel(const float* __restrict__ X,
                 const float* __restrict__ Y,
                 float* __restrict__ out,
                 unsigned char* __restrict__ ws) {
  unsigned* barI = (unsigned*)ws;             // one-time init barrier
  unsigned* cntI = (unsigned*)(ws + 512);     // 8 groups x 128B
  unsigned* bGt  = (unsigned*)(ws + 8192);    // tagged g-bias (tag in low 2 bits)
  unsigned* bFt  = (unsigned*)(ws + 24576);   // tagged f-bias
  short* Xb = (short*)(ws + 65536);           // 4096x64 bf16
  short* Yb = Xb + NN * DD;

  const int tid  = threadIdx.x;
  const int blk  = blockIdx.x;
  const int wave = tid >> 6;
  const int lane = tid & 63;
  const int i0   = blk << 4;
  const int c0   = (wave << 4) + (lane & 15); // this thread's column slot (mod 256)

  __shared__ uint2 sgl[16][NTHR];             // S_g: all 16 tiles (128 KB)
  __shared__ float red[2 * 16];               // double-buffered row accumulators
  __shared__ unsigned wcnt[2];                // per-phase wave arrival counters
  __shared__ float sh_xsq[16], sh_ysq[16];

  // ---- init: convert own 16 rows of BOTH matrices + row norms ----
  Xb[blk * NTHR + tid] = bf16_of(X[blk * NTHR + tid]);
  Yb[blk * NTHR + tid] = bf16_of(Y[blk * NTHR + tid]);
  if (tid < 32) red[tid] = 0.f;
  if (tid < 2)  wcnt[tid] = 0u;
  {
    const int row = i0 + wave;
    float vx = X[row * DD + lane];
    float vy = Y[row * DD + lane];
    float sx = vx * vx, sy = vy * vy;
#pragma unroll
    for (int o = 1; o < 64; o <<= 1) { sx += __shfl_xor(sx, o); sy += __shfl_xor(sy, o); }
    if (lane == 0) { sh_xsq[wave] = 0.5f * sx; sh_ysq[wave] = 0.5f * sy; }
  }
  __syncthreads();
  if (tid == 0) {                             // one-time fenced barrier for Xb/Yb
    __threadfence();
    arrive(cntI, blk >> 5, barI, 1);
    pollbar(barI, 8u);
  }
  __syncthreads();

  // initial g-bias (g0=0), publish index h=0 -> tag 1
  if (tid < 16)
    LLC_STU(bGt + i0 + tid, (__float_as_uint(-sh_ysq[tid] * C2f) & ~3u) | 1u);

  // ---- build S_f (regs, 16 x uint2) and S_g (LDS tiles) ----
  uint2 sf[16];
  {
    const short* ap = Xb + ((i0 + (lane & 15)) << 6) + ((lane >> 4) << 3);
    short8 a0 = *(const short8*)ap;
    short8 a1 = *(const short8*)(ap + 32);
#pragma unroll
    for (int k = 0; k < 16; ++k) {
      const int jb = (wave << 4) + (k << 8);
      const short* bp = Yb + ((jb + (lane & 15)) << 6) + ((lane >> 4) << 3);
      short8 b0 = *(const short8*)bp;
      short8 b1 = *(const short8*)(bp + 32);
      f32x4 acc = {0.f, 0.f, 0.f, 0.f};
      acc = __builtin_amdgcn_mfma_f32_16x16x32_bf16(a0, b0, acc, 0, 0, 0);
      acc = __builtin_amdgcn_mfma_f32_16x16x32_bf16(a1, b1, acc, 0, 0, 0);
      sf[k].x = __builtin_bit_cast(unsigned, __builtin_amdgcn_cvt_pkrtz(acc[0], acc[1]));
      sf[k].y = __builtin_bit_cast(unsigned, __builtin_amdgcn_cvt_pkrtz(acc[2], acc[3]));
    }
  }
  {
    const short* ap = Yb + ((i0 + (lane & 15)) << 6) + ((lane >> 4) << 3);
    short8 a0 = *(const short8*)ap;
    short8 a1 = *(const short8*)(ap + 32);
#pragma unroll
    for (int k = 0; k < 16; ++k) {
      const int jb = (wave << 4) + (k << 8);
      const short* bp = Xb + ((jb + (lane & 15)) << 6) + ((lane >> 4) << 3);
      short8 b0 = *(const short8*)bp;
      short8 b1 = *(const short8*)(bp + 32);
      f32x4 acc = {0.f, 0.f, 0.f, 0.f};
      acc = __builtin_amdgcn_mfma_f32_16x16x32_bf16(a0, b0, acc, 0, 0, 0);
      acc = __builtin_amdgcn_mfma_f32_16x16x32_bf16(a1, b1, acc, 0, 0, 0);
      const unsigned w0 = __builtin_bit_cast(unsigned, __builtin_amdgcn_cvt_pkrtz(acc[0], acc[1]));
      const unsigned w1 = __builtin_bit_cast(unsigned, __builtin_amdgcn_cvt_pkrtz(acc[2], acc[3]));
      sgl[k][tid] = make_uint2(w0, w1);
    }
  }
  __syncthreads();                            // sgl complete before steady state

  // ---- 50 iterations; NO block barriers: per-wave chunked tag-polling,
  //      wave-counter finisher does log+publish, rest race ahead ----
  for (int it = 0; it < ITERS; ++it) {
    const bool last = (it == ITERS - 1);

    // ================= f half-step (S_f in registers, red buf 0) =================
    {
      const unsigned tagIn  = tag_of(2 * it);
      const unsigned tagOut = tag_of(2 * it + 1);
      float sum[4] = {0.f, 0.f, 0.f, 0.f};
      unsigned vc[4], vn[4];
      load4(vc, bGt, c0);
      waitready(vc, bGt, c0, tagIn);
#pragma unroll
      for (int ch = 0; ch < 4; ++ch) {
        if (ch < 3) load4(vn, bGt, c0 + ((ch + 1) << 10));   // prefetch next chunk
#pragma unroll
        for (int q = 0; q < 4; ++q) {
          const int k = ch * 4 + q;
          const float bb = __uint_as_float(vc[q]);
          half2v lo = __builtin_bit_cast(half2v, sf[k].x);
          half2v hi = __builtin_bit_cast(half2v, sf[k].y);
          sum[0] += __builtin_amdgcn_exp2f(__builtin_fmaf((float)lo[0], C2f, bb));
          sum[1] += __builtin_amdgcn_exp2f(__builtin_fmaf((float)lo[1], C2f, bb));
          sum[2] += __builtin_amdgcn_exp2f(__builtin_fmaf((float)hi[0], C2f, bb));
          sum[3] += __builtin_amdgcn_exp2f(__builtin_fmaf((float)hi[1], C2f, bb));
        }
        if (ch < 3) {
          waitready(vn, bGt, c0 + ((ch + 1) << 10), tagIn);
#pragma unroll
          for (int q = 0; q < 4; ++q) vc[q] = vn[q];
        }
      }
      reduce_finish(sum, 0, bFt, i0, lane, tagOut, last, out, sh_xsq, red, wcnt);
    }

    // ================= g half-step (S_g in LDS, red buf 1) =================
    {
      const unsigned tagIn  = tag_of(2 * it + 1);
      const unsigned tagOut = tag_of(2 * it + 2);
      float sum[4] = {0.f, 0.f, 0.f, 0.f};
      unsigned vc[4], vn[4];
      load4(vc, bFt, c0);
      waitready(vc, bFt, c0, tagIn);
#pragma unroll
      for (int ch = 0; ch < 4; ++ch) {
        if (ch < 3) load4(vn, bFt, c0 + ((ch + 1) << 10));
#pragma unroll
        for (int q = 0; q < 4; ++q) {
          const int k = ch * 4 + q;
          const float bb = __uint_as_float(vc[q]);
          const uint2 w = sgl[k][tid];
          half2v lo = __builtin_bit_cast(half2v, w.x);
          half2v hi = __builtin_bit_cast(half2v, w.y);
          sum[0] += __builtin_amdgcn_exp2f(__builtin_fmaf((float)lo[0], C2f, bb));
          sum[1] += __builtin_amdgcn_exp2f(__builtin_fmaf((float)lo[1], C2f, bb));
          sum[2] += __builtin_amdgcn_exp2f(__builtin_fmaf((float)hi[0], C2f, bb));
          sum[3] += __builtin_amdgcn_exp2f(__builtin_fmaf((float)hi[1], C2f, bb));
        }
        if (ch < 3) {
          waitready(vn, bFt, c0 + ((ch + 1) << 10), tagIn);
#pragma unroll
          for (int q = 0; q < 4; ++q) vc[q] = vn[q];
        }
      }
      reduce_finish(sum, 1, bGt, i0, lane, tagOut, last, out + NN, sh_ysq, red, wcnt);
    }
  }
}

extern "C" void kernel_launch(void* const* d_in, const int* in_sizes, int n_in,
                              void* d_out, int out_size, void* d_ws, size_t ws_size,
                              hipStream_t stream) {
  const float* X = (const float*)d_in[0];
  const float* Y = (const float*)d_in[1];
  float* out = (float*)d_out;
  unsigned char* ws = (unsigned char*)d_ws;
  // zero init-barrier counters + both tagged-bias arrays (tag 0 = never-ready)
  hipMemsetAsync(d_ws, 0, 65536, stream);
  sink_kernel<<<dim3(NBLK), dim3(NTHR), 0, stream>>>(X, Y, out, ws);
}

// Round 15
// 520.431 us; speedup vs baseline: 1.3119x; 1.3119x over previous
//
#include <hip/hip_runtime.h>

#define NN 4096
#define DD 64
#define NBLK 256      // block b owns f-rows and g-rows [16b, 16b+16)
#define NTHR 1024
#define NWAVE 16
#define ITERS 50

typedef __attribute__((ext_vector_type(8))) short short8;
typedef __attribute__((ext_vector_type(4))) float f32x4;
typedef _Float16 half2v __attribute__((ext_vector_type(2)));

#define C2f     0.4808983469629878f   /* 1/(eps*ln2), eps=3 */
#define EPSLN2f 2.0794415416798359f   /* eps*ln2 */
#define TWELVEf 12.0f                 /* log2(4096) marginal term */

#define LLC_LDU(p)    __hip_atomic_load((p), __ATOMIC_RELAXED, __HIP_MEMORY_SCOPE_AGENT)
#define LLC_STU(p, v) __hip_atomic_store((p), (v), __ATOMIC_RELAXED, __HIP_MEMORY_SCOPE_AGENT)

__device__ inline short bf16_of(float f) {
  unsigned u = __float_as_uint(f);
  u += 0x7fffu + ((u >> 16) & 1u);   // RTNE, inputs finite
  return (short)(u >> 16);
}

__device__ inline void pollbar(unsigned* bar, unsigned target) {
  while (__hip_atomic_load(bar, __ATOMIC_RELAXED, __HIP_MEMORY_SCOPE_AGENT) < target)
    __builtin_amdgcn_s_sleep(2);
}
__device__ inline void arrive(unsigned* cnt, int grp, unsigned* bar, unsigned phase) {
  unsigned old = atomicAdd(&cnt[grp << 5], 1u);
  if (old == (phase << 5) - 1u) atomicAdd(bar, 1u);
}

// publish-index -> tag in {1,2,3}; 0 (memset state) never matches. A slot at index
// h is overwritten (h+2) only after every wave in the grid completed phase h+1
// (wave-granular all-to-all chain), so a reader expecting h never sees h+6.
__device__ inline unsigned tag_of(int h) { return (unsigned)(h % 3) + 1u; }

__global__ __launch_bounds__(NTHR, 4)   // 1 block/CU (145 KB LDS also enforces this)
void sink_kernel(const float* __restrict__ X,
                 const float* __restrict__ Y,
                 float* __restrict__ out,
                 unsigned char* __restrict__ ws) {
  unsigned* barI = (unsigned*)ws;             // one-time init barrier
  unsigned* cntI = (unsigned*)(ws + 512);     // 8 groups x 128B
  unsigned* bGt  = (unsigned*)(ws + 8192);    // tagged g-bias (tag in low 2 bits)
  unsigned* bFt  = (unsigned*)(ws + 24576);   // tagged f-bias
  short* Xb = (short*)(ws + 65536);           // 4096x64 bf16
  short* Yb = Xb + NN * DD;

  const int tid  = threadIdx.x;
  const int blk  = blockIdx.x;
  const int wave = tid >> 6;
  const int lane = tid & 63;
  const int m    = lane & 15;
  const int ks   = (lane >> 4) << 2;          // this lane's staged k-range [ks, ks+4)
  const int i0   = blk << 4;
  const int c0   = (wave << 4) + m;           // this thread's column slot (mod 256)

  __shared__ uint2 sgl[16][NTHR];             // S_g: all 16 tiles (128 KB)
  __shared__ float biasW[NWAVE][256];         // wave-PRIVATE staged bias (16 KB)
  __shared__ float red[2 * 16];               // f/g row accumulators
  __shared__ unsigned wcnt[2];                // MONOTONIC per-side wave counters
  __shared__ float sh_xsq[16], sh_ysq[16];

  // ---- init: convert own 16 rows of BOTH matrices + row norms ----
  Xb[blk * NTHR + tid] = bf16_of(X[blk * NTHR + tid]);
  Yb[blk * NTHR + tid] = bf16_of(Y[blk * NTHR + tid]);
  if (tid < 32) red[tid] = 0.f;
  if (tid < 2)  wcnt[tid] = 0u;
  {
    const int row = i0 + wave;
    float vx = X[row * DD + lane];
    float vy = Y[row * DD + lane];
    float sx = vx * vx, sy = vy * vy;
#pragma unroll
    for (int o = 1; o < 64; o <<= 1) { sx += __shfl_xor(sx, o); sy += __shfl_xor(sy, o); }
    if (lane == 0) { sh_xsq[wave] = 0.5f * sx; sh_ysq[wave] = 0.5f * sy; }
  }
  __syncthreads();
  if (tid == 0) {                             // one-time fenced barrier for Xb/Yb
    __threadfence();
    arrive(cntI, blk >> 5, barI, 1);
    pollbar(barI, 8u);
  }
  __syncthreads();

  // initial g-bias (g0=0), publish index h=0 -> tag 1
  if (tid < 16)
    LLC_STU(bGt + i0 + tid, (__float_as_uint(-sh_ysq[tid] * C2f) & ~3u) | 1u);

  // ---- build S_f (regs, 16 x uint2) and S_g (LDS tiles; sgl[k][tid] is
  //      written and read by the SAME thread -> no cross-thread dependency) ----
  uint2 sf[16];
  {
    const short* ap = Xb + ((i0 + m) << 6) + ((lane >> 4) << 3);
    short8 a0 = *(const short8*)ap;
    short8 a1 = *(const short8*)(ap + 32);
#pragma unroll
    for (int k = 0; k < 16; ++k) {
      const int jb = (wave << 4) + (k << 8);
      const short* bp = Yb + ((jb + m) << 6) + ((lane >> 4) << 3);
      short8 b0 = *(const short8*)bp;
      short8 b1 = *(const short8*)(bp + 32);
      f32x4 acc = {0.f, 0.f, 0.f, 0.f};
      acc = __builtin_amdgcn_mfma_f32_16x16x32_bf16(a0, b0, acc, 0, 0, 0);
      acc = __builtin_amdgcn_mfma_f32_16x16x32_bf16(a1, b1, acc, 0, 0, 0);
      sf[k].x = __builtin_bit_cast(unsigned, __builtin_amdgcn_cvt_pkrtz(acc[0], acc[1]));
      sf[k].y = __builtin_bit_cast(unsigned, __builtin_amdgcn_cvt_pkrtz(acc[2], acc[3]));
    }
  }
  {
    const short* ap = Yb + ((i0 + m) << 6) + ((lane >> 4) << 3);
    short8 a0 = *(const short8*)ap;
    short8 a1 = *(const short8*)(ap + 32);
#pragma unroll
    for (int k = 0; k < 16; ++k) {
      const int jb = (wave << 4) + (k << 8);
      const short* bp = Xb + ((jb + m) << 6) + ((lane >> 4) << 3);
      short8 b0 = *(const short8*)bp;
      short8 b1 = *(const short8*)(bp + 32);
      f32x4 acc = {0.f, 0.f, 0.f, 0.f};
      acc = __builtin_amdgcn_mfma_f32_16x16x32_bf16(a0, b0, acc, 0, 0, 0);
      acc = __builtin_amdgcn_mfma_f32_16x16x32_bf16(a1, b1, acc, 0, 0, 0);
      const unsigned w0 = __builtin_bit_cast(unsigned, __builtin_amdgcn_cvt_pkrtz(acc[0], acc[1]));
      const unsigned w1 = __builtin_bit_cast(unsigned, __builtin_amdgcn_cvt_pkrtz(acc[2], acc[3]));
      sgl[k][tid] = make_uint2(w0, w1);
    }
  }
  __syncthreads();                            // red/wcnt zeros + init done everywhere

  // ---- 50 iterations; ZERO block barriers. Per-wave: poll own 4 slots ->
  //      wave-private LDS stage -> compute -> LDS-atomic reduce -> monotonic
  //      wave-counter; last wave (natural straggler) does log+publish. ----
  for (int it = 0; it < ITERS; ++it) {
    const bool last = (it == ITERS - 1);
    const unsigned tgt = (unsigned)((it << 4) + 15);   // 16*(it+1)-1

    // ================= f half-step (S_f in registers, red[0:16]) =================
    {
      const unsigned tagIn  = tag_of(2 * it);
      const unsigned tagOut = tag_of(2 * it + 1);
      unsigned v[4];
#pragma unroll
      for (int r = 0; r < 4; ++r) v[r] = LLC_LDU(bGt + c0 + ((ks + r) << 8));
      for (;;) {
        unsigned miss = 0;
#pragma unroll
        for (int r = 0; r < 4; ++r) miss |= ((v[r] & 3u) != tagIn) ? (1u << r) : 0u;
        if (!miss) break;
        __builtin_amdgcn_s_sleep(1);
#pragma unroll
        for (int r = 0; r < 4; ++r)
          if (miss & (1u << r)) v[r] = LLC_LDU(bGt + c0 + ((ks + r) << 8));
      }
#pragma unroll
      for (int r = 0; r < 4; ++r) biasW[wave][((ks + r) << 4) + m] = __uint_as_float(v[r]);
      asm volatile("s_waitcnt lgkmcnt(0)" ::: "memory");   // same-wave stage visible

      float sum[4] = {0.f, 0.f, 0.f, 0.f};
#pragma unroll
      for (int k = 0; k < 16; ++k) {
        const float bb = biasW[wave][(k << 4) + m];
        half2v lo = __builtin_bit_cast(half2v, sf[k].x);
        half2v hi = __builtin_bit_cast(half2v, sf[k].y);
        sum[0] += __builtin_amdgcn_exp2f(__builtin_fmaf((float)lo[0], C2f, bb));
        sum[1] += __builtin_amdgcn_exp2f(__builtin_fmaf((float)lo[1], C2f, bb));
        sum[2] += __builtin_amdgcn_exp2f(__builtin_fmaf((float)hi[0], C2f, bb));
        sum[3] += __builtin_amdgcn_exp2f(__builtin_fmaf((float)hi[1], C2f, bb));
      }
#pragma unroll
      for (int o = 1; o <= 8; o <<= 1)
#pragma unroll
        for (int r = 0; r < 4; ++r) sum[r] += __shfl_xor(sum[r], o);
      if (m == 0)
#pragma unroll
        for (int r = 0; r < 4; ++r) atomicAdd(&red[((lane >> 4) << 2) + r], sum[r]);
      unsigned old = 0;
      if (lane == 0)
        old = __hip_atomic_fetch_add(&wcnt[0], 1u, __ATOMIC_ACQ_REL,
                                     __HIP_MEMORY_SCOPE_WORKGROUP);
      old = __shfl(old, 0);
      if (old == tgt) {                       // last-arriving wave finishes
        if (lane < 16) {
          const float t = red[lane];
          red[lane] = 0.f;                    // re-arm BEFORE publish (causal order)
          asm volatile("s_waitcnt lgkmcnt(0)" ::: "memory");
          const float bc = TWELVEf - __builtin_amdgcn_logf(t);
          LLC_STU(bFt + i0 + lane, (__float_as_uint(bc) & ~3u) | tagOut);
          if (last) out[i0 + lane] = sh_xsq[lane] + EPSLN2f * bc;
        }
      }
    }

    // ================= g half-step (S_g in LDS, red[16:32]) =================
    {
      const unsigned tagIn  = tag_of(2 * it + 1);
      const unsigned tagOut = tag_of(2 * it + 2);
      unsigned v[4];
#pragma unroll
      for (int r = 0; r < 4; ++r) v[r] = LLC_LDU(bFt + c0 + ((ks + r) << 8));
      for (;;) {
        unsigned miss = 0;
#pragma unroll
        for (int r = 0; r < 4; ++r) miss |= ((v[r] & 3u) != tagIn) ? (1u << r) : 0u;
        if (!miss) break;
        __builtin_amdgcn_s_sleep(1);
#pragma unroll
        for (int r = 0; r < 4; ++r)
          if (miss & (1u << r)) v[r] = LLC_LDU(bFt + c0 + ((ks + r) << 8));
      }
#pragma unroll
      for (int r = 0; r < 4; ++r) biasW[wave][((ks + r) << 4) + m] = __uint_as_float(v[r]);
      asm volatile("s_waitcnt lgkmcnt(0)" ::: "memory");

      float sum[4] = {0.f, 0.f, 0.f, 0.f};
#pragma unroll
      for (int k = 0; k < 16; ++k) {
        const float bb = biasW[wave][(k << 4) + m];
        const uint2 w = sgl[k][tid];
        half2v lo = __builtin_bit_cast(half2v, w.x);
        half2v hi = __builtin_bit_cast(half2v, w.y);
        sum[0] += __builtin_amdgcn_exp2f(__builtin_fmaf((float)lo[0], C2f, bb));
        sum[1] += __builtin_amdgcn_exp2f(__builtin_fmaf((float)lo[1], C2f, bb));
        sum[2] += __builtin_amdgcn_exp2f(__builtin_fmaf((float)hi[0], C2f, bb));
        sum[3] += __builtin_amdgcn_exp2f(__builtin_fmaf((float)hi[1], C2f, bb));
      }
#pragma unroll
      for (int o = 1; o <= 8; o <<= 1)
#pragma unroll
        for (int r = 0; r < 4; ++r) sum[r] += __shfl_xor(sum[r], o);
      if (m == 0)
#pragma unroll
        for (int r = 0; r < 4; ++r) atomicAdd(&red[16 + ((lane >> 4) << 2) + r], sum[r]);
      unsigned old = 0;
      if (lane == 0)
        old = __hip_atomic_fetch_add(&wcnt[1], 1u, __ATOMIC_ACQ_REL,
                                     __HIP_MEMORY_SCOPE_WORKGROUP);
      old = __shfl(old, 0);
      if (old == tgt) {
        if (lane < 16) {
          const float t = red[16 + lane];
          red[16 + lane] = 0.f;
          asm volatile("s_waitcnt lgkmcnt(0)" ::: "memory");
          const float bc = TWELVEf - __builtin_amdgcn_logf(t);
          LLC_STU(bGt + i0 + lane, (__float_as_uint(bc) & ~3u) | tagOut);
          if (last) out[NN + i0 + lane] = sh_ysq[lane] + EPSLN2f * bc;
        }
      }
    }
  }
}

extern "C" void kernel_launch(void* const* d_in, const int* in_sizes, int n_in,
                              void* d_out, int out_size, void* d_ws, size_t ws_size,
                              hipStream_t stream) {
  const float* X = (const float*)d_in[0];
  const float* Y = (const float*)d_in[1];
  float* out = (float*)d_out;
  unsigned char* ws = (unsigned char*)d_ws;
  // zero init-barrier counters + both tagged-bias arrays (tag 0 = never-ready)
  hipMemsetAsync(d_ws, 0, 65536, stream);
  sink_kernel<<<dim3(NBLK), dim3(NTHR), 0, stream>>>(X, Y, out, ws);
}

// Round 16
// 377.073 us; speedup vs baseline: 1.8106x; 1.3802x over previous
//
#include <hip/hip_runtime.h>

#define NN 4096
#define DD 64
#define NBLK 256      // merged roles: block b owns f-rows and g-rows [16b, 16b+16)
#define NTHR 1024
#define NWAVE 16
#define ITERS 50

typedef __attribute__((ext_vector_type(8))) short short8;
typedef __attribute__((ext_vector_type(4))) float f32x4;

#define C2f     0.4808983469629878f   /* 1/(eps*ln2), eps=3 */
#define EPSLN2f 2.0794415416798359f   /* eps*ln2 */
#define TWELVEf 12.0f                 /* log2(4096) marginal term */

#define LLC_LDU(p)    __hip_atomic_load((p), __ATOMIC_RELAXED, __HIP_MEMORY_SCOPE_AGENT)
#define LLC_STU(p, v) __hip_atomic_store((p), (v), __ATOMIC_RELAXED, __HIP_MEMORY_SCOPE_AGENT)

__device__ inline short bf16_of(float f) {
  unsigned u = __float_as_uint(f);
  u += 0x7fffu + ((u >> 16) & 1u);   // RTNE, inputs finite
  return (short)(u >> 16);
}
// pack two positive floats as bf16 pair (RTNE)
__device__ inline unsigned pack_bf16(float e0, float e1) {
  return ((unsigned)(unsigned short)bf16_of(e1) << 16) |
         (unsigned)(unsigned short)bf16_of(e0);
}

__device__ inline void pollbar(unsigned* bar, unsigned target) {
  while (__hip_atomic_load(bar, __ATOMIC_RELAXED, __HIP_MEMORY_SCOPE_AGENT) < target)
    __builtin_amdgcn_s_sleep(2);
}
__device__ inline void arrive(unsigned* cnt, int grp, unsigned* bar, unsigned phase) {
  unsigned old = atomicAdd(&cnt[grp << 5], 1u);
  if (old == (phase << 5) - 1u) atomicAdd(bar, 1u);
}

// publish-index -> tag in {1,2,3}; 0 (memset state) never matches; a slot at index h
// is only overwritten (h+2) after all consumers passed the h+1 all-to-all.
__device__ inline unsigned tag_of(int h) { return (unsigned)(h % 3) + 1u; }

// Fused poll+stage with parallel retry; stores w = exp2(bias) (the only exp2s
// of the whole half-step: 4 per thread). Tag bits = 3ulp bias noise, negligible.
__device__ __forceinline__ void poll_stage(unsigned* __restrict__ src, unsigned tagIn,
                                           float* w_lds, int tid) {
  unsigned v[4];
#pragma unroll
  for (int q = 0; q < 4; ++q) v[q] = LLC_LDU(src + tid + (q << 10));
  for (;;) {
    unsigned miss = 0;
#pragma unroll
    for (int q = 0; q < 4; ++q) miss |= ((v[q] & 3u) != tagIn) ? (1u << q) : 0u;
    if (!miss) break;
    __builtin_amdgcn_s_sleep(1);
#pragma unroll
    for (int q = 0; q < 4; ++q)
      if (miss & (1u << q)) v[q] = LLC_LDU(src + tid + (q << 10));
  }
#pragma unroll
  for (int q = 0; q < 4; ++q)
    w_lds[tid + (q << 10)] = __builtin_amdgcn_exp2f(__uint_as_float(v[q]));
}

__global__ __launch_bounds__(NTHR, 4)   // 1 block/CU (148 KB LDS also enforces this)
void sink_kernel(const float* __restrict__ X,
                 const float* __restrict__ Y,
                 float* __restrict__ out,
                 unsigned char* __restrict__ ws) {
  unsigned* barI = (unsigned*)ws;             // one-time init barrier
  unsigned* cntI = (unsigned*)(ws + 512);     // 8 groups x 128B
  unsigned* bGt  = (unsigned*)(ws + 8192);    // tagged g-bias (tag in low 2 bits)
  unsigned* bFt  = (unsigned*)(ws + 24576);   // tagged f-bias
  short* Xb = (short*)(ws + 65536);           // 4096x64 bf16
  short* Yb = Xb + NN * DD;

  const int tid  = threadIdx.x;
  const int blk  = blockIdx.x;
  const int wave = tid >> 6;
  const int lane = tid & 63;
  const int i0   = blk << 4;
  const int c0   = (wave << 4) + (lane & 15); // this thread's column slot (mod 256)

  __shared__ uint2 sgl[16][NTHR];             // E_g: all 16 tiles, packed bf16 (128 KB)
  __shared__ float w_lds[NN];                 // staged w = exp2(bias) (16 KB)
  __shared__ float red[16];                   // row accumulators
  __shared__ float sh_xsq[16], sh_ysq[16];

  // ---- init: convert own 16 rows of BOTH matrices + row norms ----
  Xb[blk * NTHR + tid] = bf16_of(X[blk * NTHR + tid]);
  Yb[blk * NTHR + tid] = bf16_of(Y[blk * NTHR + tid]);
  if (tid < 16) red[tid] = 0.f;
  {
    const int row = i0 + wave;
    float vx = X[row * DD + lane];
    float vy = Y[row * DD + lane];
    float sx = vx * vx, sy = vy * vy;
#pragma unroll
    for (int o = 1; o < 64; o <<= 1) { sx += __shfl_xor(sx, o); sy += __shfl_xor(sy, o); }
    if (lane == 0) { sh_xsq[wave] = 0.5f * sx; sh_ysq[wave] = 0.5f * sy; }
  }
  __syncthreads();
  if (tid == 0) {                             // one-time fenced barrier for Xb/Yb
    __threadfence();
    arrive(cntI, blk >> 5, barI, 1);
    pollbar(barI, 8u);
  }
  __syncthreads();

  // initial g-bias (g0=0), publish index h=0 -> tag 1
  if (tid < 16)
    LLC_STU(bGt + i0 + tid, (__float_as_uint(-sh_ysq[tid] * C2f) & ~3u) | 1u);

  // ---- build E_f (regs) and E_g (LDS): E = exp2(dot*c), bf16-packed.
  //      exp2 args bounded (|dot*c| <= ~22) -> E in 2^±22, bf16-safe. ----
  uint2 sf[16];
  {
    const short* ap = Xb + ((i0 + (lane & 15)) << 6) + ((lane >> 4) << 3);
    short8 a0 = *(const short8*)ap;
    short8 a1 = *(const short8*)(ap + 32);
#pragma unroll
    for (int k = 0; k < 16; ++k) {
      const int jb = (wave << 4) + (k << 8);
      const short* bp = Yb + ((jb + (lane & 15)) << 6) + ((lane >> 4) << 3);
      short8 b0 = *(const short8*)bp;
      short8 b1 = *(const short8*)(bp + 32);
      f32x4 acc = {0.f, 0.f, 0.f, 0.f};
      acc = __builtin_amdgcn_mfma_f32_16x16x32_bf16(a0, b0, acc, 0, 0, 0);
      acc = __builtin_amdgcn_mfma_f32_16x16x32_bf16(a1, b1, acc, 0, 0, 0);
      sf[k].x = pack_bf16(__builtin_amdgcn_exp2f(acc[0] * C2f),
                          __builtin_amdgcn_exp2f(acc[1] * C2f));
      sf[k].y = pack_bf16(__builtin_amdgcn_exp2f(acc[2] * C2f),
                          __builtin_amdgcn_exp2f(acc[3] * C2f));
    }
  }
  {
    const short* ap = Yb + ((i0 + (lane & 15)) << 6) + ((lane >> 4) << 3);
    short8 a0 = *(const short8*)ap;
    short8 a1 = *(const short8*)(ap + 32);
#pragma unroll
    for (int k = 0; k < 16; ++k) {
      const int jb = (wave << 4) + (k << 8);
      const short* bp = Xb + ((jb + (lane & 15)) << 6) + ((lane >> 4) << 3);
      short8 b0 = *(const short8*)bp;
      short8 b1 = *(const short8*)(bp + 32);
      f32x4 acc = {0.f, 0.f, 0.f, 0.f};
      acc = __builtin_amdgcn_mfma_f32_16x16x32_bf16(a0, b0, acc, 0, 0, 0);
      acc = __builtin_amdgcn_mfma_f32_16x16x32_bf16(a1, b1, acc, 0, 0, 0);
      const unsigned w0 = pack_bf16(__builtin_amdgcn_exp2f(acc[0] * C2f),
                                    __builtin_amdgcn_exp2f(acc[1] * C2f));
      const unsigned w1 = pack_bf16(__builtin_amdgcn_exp2f(acc[2] * C2f),
                                    __builtin_amdgcn_exp2f(acc[3] * C2f));
      sgl[k][tid] = make_uint2(w0, w1);
    }
  }

  // publish indices: bGt gets h=0 (init) and h=2it+2 (g_it); bFt gets h=2it+1 (f_it).
  // f at it consumes bGt h=2it; g at it consumes bFt h=2it+1.
  // Published bias b = (pot - sq)*C2f = 12 - log2(Sigma), Sigma = sum_j E_ij * w_j.
  for (int it = 0; it < ITERS; ++it) {
    const bool last = (it == ITERS - 1);

    // ================= f half-step (E_f in registers) =================
    {
      const unsigned tagIn  = tag_of(2 * it);
      const unsigned tagOut = tag_of(2 * it + 1);
      poll_stage(bGt, tagIn, w_lds, tid);
      __syncthreads();
      float sum[4] = {0.f, 0.f, 0.f, 0.f};
#pragma unroll
      for (int k = 0; k < 16; ++k) {
        const float w = w_lds[c0 + (k << 8)];       // 4-way broadcast, conflict-free
        const unsigned p0 = sf[k].x, p1 = sf[k].y;
        sum[0] = __builtin_fmaf(__uint_as_float(p0 << 16),          w, sum[0]);
        sum[1] = __builtin_fmaf(__uint_as_float(p0 & 0xffff0000u),  w, sum[1]);
        sum[2] = __builtin_fmaf(__uint_as_float(p1 << 16),          w, sum[2]);
        sum[3] = __builtin_fmaf(__uint_as_float(p1 & 0xffff0000u),  w, sum[3]);
      }
#pragma unroll
      for (int o = 1; o <= 8; o <<= 1)
#pragma unroll
        for (int r = 0; r < 4; ++r) sum[r] += __shfl_xor(sum[r], o);
      if ((lane & 15) == 0)
#pragma unroll
        for (int r = 0; r < 4; ++r) atomicAdd(&red[((lane >> 4) << 2) + r], sum[r]);
      __syncthreads();
      if (tid < 16) {
        const float bc = TWELVEf - __builtin_amdgcn_logf(red[tid]); // v_log_f32 = log2
        LLC_STU(bFt + i0 + tid, (__float_as_uint(bc) & ~3u) | tagOut);
        red[tid] = 0.f;                                      // re-arm for g half
        if (last) out[i0 + tid] = sh_xsq[tid] + EPSLN2f * bc;
      }
      // no extra sync: g's stage-sync is gated on tid<16 arriving after the zero
    }

    // ================= g half-step (E_g in LDS) =================
    {
      const unsigned tagIn  = tag_of(2 * it + 1);
      const unsigned tagOut = tag_of(2 * it + 2);
      poll_stage(bFt, tagIn, w_lds, tid);
      __syncthreads();
      float sum[4] = {0.f, 0.f, 0.f, 0.f};
#pragma unroll
      for (int k = 0; k < 16; ++k) {
        const float w = w_lds[c0 + (k << 8)];
        const uint2 e = sgl[k][tid];
        sum[0] = __builtin_fmaf(__uint_as_float(e.x << 16),         w, sum[0]);
        sum[1] = __builtin_fmaf(__uint_as_float(e.x & 0xffff0000u), w, sum[1]);
        sum[2] = __builtin_fmaf(__uint_as_float(e.y << 16),         w, sum[2]);
        sum[3] = __builtin_fmaf(__uint_as_float(e.y & 0xffff0000u), w, sum[3]);
      }
#pragma unroll
      for (int o = 1; o <= 8; o <<= 1)
#pragma unroll
        for (int r = 0; r < 4; ++r) sum[r] += __shfl_xor(sum[r], o);
      if ((lane & 15) == 0)
#pragma unroll
        for (int r = 0; r < 4; ++r) atomicAdd(&red[((lane >> 4) << 2) + r], sum[r]);
      __syncthreads();
      if (tid < 16) {
        const float bc = TWELVEf - __builtin_amdgcn_logf(red[tid]);
        LLC_STU(bGt + i0 + tid, (__float_as_uint(bc) & ~3u) | tagOut);
        red[tid] = 0.f;                                      // re-arm for next f half
        if (last) out[NN + i0 + tid] = sh_ysq[tid] + EPSLN2f * bc;
      }
      // next f stage-sync gates on tid<16 as above
    }
  }
}

extern "C" void kernel_launch(void* const* d_in, const int* in_sizes, int n_in,
                              void* d_out, int out_size, void* d_ws, size_t ws_size,
                              hipStream_t stream) {
  const float* X = (const float*)d_in[0];
  const float* Y = (const float*)d_in[1];
  float* out = (float*)d_out;
  unsigned char* ws = (unsigned char*)d_ws;
  // zero init-barrier counters + both tagged-bias arrays (tag 0 = never-ready)
  hipMemsetAsync(d_ws, 0, 65536, stream);
  sink_kernel<<<dim3(NBLK), dim3(NTHR), 0, stream>>>(X, Y, out, ws);
}